// Round 7
// baseline (52.733 us; speedup 1.0000x reference)
//
#include <hip/hip_runtime.h>

#define NT 8
#define ND 16
#define NH 16
#define NW 16
#define NC 32
#define NB 65536

typedef __attribute__((ext_vector_type(8))) _Float16 half8;
typedef __attribute__((ext_vector_type(4))) _Float16 half4;
typedef __attribute__((ext_vector_type(2))) _Float16 half2v;

union H8 {
    half8 v;
    half2v h2[4];
};

// Span-based per-dim setup: control-point span b..b+3 (always in-bounds) and
// 4 weights aligned to the span, with linear-extrapolation padding folded in
// and zero-padding at the edges. Validated (absmax 7.8e-3) in rounds 3-6.
template <int N>
__device__ __forceinline__ void dim_setup_span(float u, int& b, float w[4]) {
    float s = u * (float)(N - 1);
    float fi = floorf(s);
    fi = fminf(fmaxf(fi, 0.0f), (float)(N - 2));
    float t = s - fi;
    int i = (int)fi;
    float t2 = t * t, t3 = t2 * t;
    const float c6 = 1.0f / 6.0f;
    float w0 = (1.0f - 3.0f * t + 3.0f * t2 - t3) * c6;
    float w1 = (4.0f - 6.0f * t2 + 3.0f * t3) * c6;
    float w2 = (1.0f + 3.0f * t + 3.0f * t2 - 3.0f * t3) * c6;
    float w3 = t3 * c6;
    if (i == 0) {
        b = 0;
        w[0] = w1 + 2.0f * w0; w[1] = w2 - w0; w[2] = w3; w[3] = 0.0f;
    } else if (i == N - 2) {
        b = N - 4;
        w[0] = 0.0f; w[1] = w0; w[2] = w1 - w3; w[3] = w2 + 2.0f * w3;
    } else {
        b = i - 1;
        w[0] = w0; w[1] = w1; w[2] = w2; w[3] = w3;
    }
}

// f32 grid (4 MiB) -> fp16 grid (2 MiB) in workspace, RNE.
__global__ __launch_bounds__(256) void convert_fp16_kernel(
    const float4* __restrict__ g, half4* __restrict__ hg) {
    int i = blockIdx.x * blockDim.x + threadIdx.x;
    float4 v = g[i];
    half4 h;
    h[0] = (_Float16)v.x;
    h[1] = (_Float16)v.y;
    h[2] = (_Float16)v.z;
    h[3] = (_Float16)v.w;
    hg[i] = h;
}

// 16 lanes per query; lane s takes 16B of the contiguous 256B w-span
// (w-point s>>2, channels 8*(s&3)..+8); one half8 load per (t,d,h) point-row.
// ILP restructure: (i,j) flattened to 16 groups of 4 k-loads; ping-pong A/B
// so 8 loads (8KB/wave) are in flight while computing the previous group.
// Packed-f16 accumulation (v_pk_fma_f16), flushed to f32 after groups 7/15.

// group g = (i<<2)|j ; half8 strides: t=16384, d=1024, h=64
#define LOADG(R, g)                                                       \
    do {                                                                  \
        const half8* p_ = g0 + (((g) >> 2) * 16384 + ((g) & 3) * 1024);   \
        R##0 = p_[0];                                                     \
        R##1 = p_[64];                                                    \
        R##2 = p_[128];                                                   \
        R##3 = p_[192];                                                   \
    } while (0)

#define COMPK(R, kk)                                                      \
    do {                                                                  \
        H8 U_;                                                            \
        U_.v = R;                                                         \
        half2v uw_ = wtd2 * whW2[kk];                                     \
        a01 += U_.h2[0] * uw_;                                            \
        a23 += U_.h2[1] * uw_;                                            \
        a45 += U_.h2[2] * uw_;                                            \
        a67 += U_.h2[3] * uw_;                                            \
    } while (0)

#define COMPG(R, g)                                                       \
    do {                                                                  \
        _Float16 wtdh_ = (_Float16)(wtv[(g) >> 2] * wdv[(g) & 3]);        \
        half2v wtd2 = {wtdh_, wtdh_};                                     \
        COMPK(R##0, 0);                                                   \
        COMPK(R##1, 1);                                                   \
        COMPK(R##2, 2);                                                   \
        COMPK(R##3, 3);                                                   \
    } while (0)

#define FLUSH()                                                           \
    do {                                                                  \
        facc[0] += (float)a01[0]; facc[1] += (float)a01[1];               \
        facc[2] += (float)a23[0]; facc[3] += (float)a23[1];               \
        facc[4] += (float)a45[0]; facc[5] += (float)a45[1];               \
        facc[6] += (float)a67[0]; facc[7] += (float)a67[1];               \
        a01 = (half2v){0, 0}; a23 = (half2v){0, 0};                       \
        a45 = (half2v){0, 0}; a67 = (half2v){0, 0};                       \
    } while (0)

__global__ __launch_bounds__(256) void spline4d_fp16_kernel(
    const float* __restrict__ u, const half8* __restrict__ grid,
    float4* __restrict__ out) {
    int tid = blockIdx.x * blockDim.x + threadIdx.x;
    int q = tid >> 4;   // query index
    int s = tid & 15;   // lane-within-query

    float4 uu = reinterpret_cast<const float4*>(u)[q];

    int bt, bd, bh, bw;
    float wtv[4], wdv[4], whv[4], wwv[4];
    dim_setup_span<NT>(uu.x, bt, wtv);
    dim_setup_span<ND>(uu.y, bd, wdv);
    dim_setup_span<NH>(uu.z, bh, whv);
    dim_setup_span<NW>(uu.w, bw, wwv);

    // this lane's w-point weight (static-index select chain)
    int wp = s >> 2;
    float wlane = (wp & 2) ? ((wp & 1) ? wwv[3] : wwv[2])
                           : ((wp & 1) ? wwv[1] : wwv[0]);

    // pre-packed half2 broadcast of (h-weight x lane w-weight)
    half2v whW2[4];
#pragma unroll
    for (int k = 0; k < 4; ++k) {
        _Float16 h = (_Float16)(whv[k] * wlane);
        whW2[k][0] = h;
        whW2[k][1] = h;
    }

    // half8 index: point P = ((t*ND+d)*NH+h)*NW+w occupies half8 [4P, 4P+4);
    // lane covers span byte offset 16*s -> half8 index 4*P_base + s.
    const half8* g0 =
        grid + (((((bt * ND + bd) * NH + bh) * NW + bw) << 2) + s);

    float facc[8];
#pragma unroll
    for (int c = 0; c < 8; ++c) facc[c] = 0.0f;

    half2v a01 = {0, 0}, a23 = {0, 0}, a45 = {0, 0}, a67 = {0, 0};

    half8 A0, A1, A2, A3, B0, B1, B2, B3;

    LOADG(A, 0);
    LOADG(B, 1);  COMPG(A, 0);
    LOADG(A, 2);  COMPG(B, 1);
    LOADG(B, 3);  COMPG(A, 2);
    LOADG(A, 4);  COMPG(B, 3);
    LOADG(B, 5);  COMPG(A, 4);
    LOADG(A, 6);  COMPG(B, 5);
    LOADG(B, 7);  COMPG(A, 6);
    LOADG(A, 8);  COMPG(B, 7);  FLUSH();
    LOADG(B, 9);  COMPG(A, 8);
    LOADG(A, 10); COMPG(B, 9);
    LOADG(B, 11); COMPG(A, 10);
    LOADG(A, 12); COMPG(B, 11);
    LOADG(B, 13); COMPG(A, 12);
    LOADG(A, 14); COMPG(B, 13);
    LOADG(B, 15); COMPG(A, 14);
    COMPG(B, 15); FLUSH();

    // combine the 4 w-points: lanes s, s^4, s^8, s^12 share channels 8*(s&3)
#pragma unroll
    for (int c = 0; c < 8; ++c) {
        facc[c] += __shfl_xor(facc[c], 4);
        facc[c] += __shfl_xor(facc[c], 8);
    }

    // lanes 0..3 hold channels 8s..8s+7 -> two float4 stores each
    if (s < 4) {
        out[q * 8 + s * 2] = make_float4(facc[0], facc[1], facc[2], facc[3]);
        out[q * 8 + s * 2 + 1] = make_float4(facc[4], facc[5], facc[6], facc[7]);
    }
}

// Fallback (workspace too small): f32 gather kernel (round-1 version, passed).
#define SW 8
#define SH (NW * SW)
#define SD (NH * SH)
#define ST (ND * SD)

template <int N, int STRIDE>
__device__ __forceinline__ void dim_setup(float u, int idx[4], float w[4]) {
    float s = u * (float)(N - 1);
    float fi = floorf(s);
    fi = fminf(fmaxf(fi, 0.0f), (float)(N - 2));
    float t = s - fi;
    int i = (int)fi;
    float t2 = t * t, t3 = t2 * t;
    const float c6 = 1.0f / 6.0f;
    float w0 = (1.0f - 3.0f * t + 3.0f * t2 - t3) * c6;
    float w1 = (4.0f - 6.0f * t2 + 3.0f * t3) * c6;
    float w2 = (1.0f + 3.0f * t + 3.0f * t2 - 3.0f * t3) * c6;
    float w3 = t3 * c6;
    int i0, i1, i2, i3;
    float v0, v1, v2, v3;
    if (i == 0) {
        i0 = 0; i1 = 1; i2 = 2; i3 = 2;
        v0 = w1 + 2.0f * w0; v1 = w2 - w0; v2 = w3; v3 = 0.0f;
    } else if (i == N - 2) {
        i0 = N - 3; i1 = N - 2; i2 = N - 1; i3 = N - 1;
        v0 = w0; v1 = w1 - w3; v2 = w2 + 2.0f * w3; v3 = 0.0f;
    } else {
        i0 = i - 1; i1 = i; i2 = i + 1; i3 = i + 2;
        v0 = w0; v1 = w1; v2 = w2; v3 = w3;
    }
    idx[0] = i0 * STRIDE; idx[1] = i1 * STRIDE;
    idx[2] = i2 * STRIDE; idx[3] = i3 * STRIDE;
    w[0] = v0; w[1] = v1; w[2] = v2; w[3] = v3;
}

__global__ __launch_bounds__(256, 4) void spline4d_f32_kernel(
    const float* __restrict__ u, const float4* __restrict__ grid,
    float4* __restrict__ out) {
    int tid = blockIdx.x * blockDim.x + threadIdx.x;
    int q = tid >> 3;
    int s = tid & 7;

    float4 uu = reinterpret_cast<const float4*>(u)[q];

    int it[4], id[4], ih[4], iw[4];
    float wt[4], wd[4], wh[4], ww[4];
    dim_setup<NT, ST>(uu.x, it, wt);
    dim_setup<ND, SD>(uu.y, id, wd);
    dim_setup<NH, SH>(uu.z, ih, wh);
    dim_setup<NW, SW>(uu.w, iw, ww);

    float4 acc = make_float4(0.0f, 0.0f, 0.0f, 0.0f);

#pragma unroll
    for (int i = 0; i < 4; ++i) {
        int offt = it[i];
        float wti = wt[i];
#pragma unroll
        for (int j = 0; j < 4; ++j) {
            int offtd = offt + id[j];
            float wij = wti * wd[j];
#pragma unroll
            for (int k = 0; k < 4; ++k) {
                int offtdh = offtd + ih[k] + s;
                float wijk = wij * wh[k];
#pragma unroll
                for (int l = 0; l < 4; ++l) {
                    float4 p = grid[offtdh + iw[l]];
                    float wgt = wijk * ww[l];
                    acc.x = fmaf(wgt, p.x, acc.x);
                    acc.y = fmaf(wgt, p.y, acc.y);
                    acc.z = fmaf(wgt, p.z, acc.z);
                    acc.w = fmaf(wgt, p.w, acc.w);
                }
            }
        }
    }

    out[q * 8 + s] = acc;
}

extern "C" void kernel_launch(void* const* d_in, const int* in_sizes, int n_in,
                              void* d_out, int out_size, void* d_ws, size_t ws_size,
                              hipStream_t stream) {
    const float* u = (const float*)d_in[0];
    const float* grid_f32 = (const float*)d_in[1];
    float4* out = (float4*)d_out;

    const size_t n_grid_floats = (size_t)NT * ND * NH * NW * NC;  // 1,048,576
    const size_t hg_bytes = n_grid_floats * 2;                    // 2 MiB

    if (ws_size >= hg_bytes) {
        int cvt_blocks = (int)(n_grid_floats / 4 / 256);  // 1024
        convert_fp16_kernel<<<cvt_blocks, 256, 0, stream>>>(
            (const float4*)grid_f32, (half4*)d_ws);
        // 16 threads per query, 256/block -> 16 queries/block, 4096 blocks
        int nblocks = NB * 16 / 256;
        spline4d_fp16_kernel<<<nblocks, 256, 0, stream>>>(
            u, (const half8*)d_ws, out);
    } else {
        int nblocks = NB * 8 / 256;
        spline4d_f32_kernel<<<nblocks, 256, 0, stream>>>(
            u, (const float4*)grid_f32, out);
    }
}